// Round 1
// baseline (55.393 us; speedup 1.0000x reference)
//
#include <hip/hip_runtime.h>
#include <math.h>

#define BB 4
#define TT 1024
#define HH 16
#define NROWS 64   // 2*BINS table rows

#define PI_F    3.14159265358979323846f
#define TWOPI_F 6.28318530717958647692f

// ---------------- Kernel A: global eta range ----------------
__global__ void QuantizedRPE_range_kernel(const float* __restrict__ coords,
                                          float* __restrict__ ws) {
    int lane = threadIdx.x & 63;
    int b = threadIdx.x >> 6;  // 4 waves, one batch each
    float mx = -1e30f, mn = 1e30f;
    for (int t = lane; t < TT; t += 64) {
        float e = coords[(size_t)(b * TT + t) * 2];
        mx = fmaxf(mx, e);
        mn = fminf(mn, e);
    }
    #pragma unroll
    for (int m = 32; m; m >>= 1) {
        mx = fmaxf(mx, __shfl_xor(mx, m));
        mn = fminf(mn, __shfl_xor(mn, m));
    }
    __shared__ float sr[BB];
    if (lane == 0) sr[b] = mx - mn;
    __syncthreads();
    if (threadIdx.x == 0) {
        float r = fmaxf(fmaxf(sr[0], sr[1]), fmaxf(sr[2], sr[3]));
        ws[0] = fmaxf(r, 1e-6f);
    }
}

// ---------------- Kernel B: bias fill ----------------
__global__ __launch_bounds__(256) void QuantizedRPE_fill_kernel(
        const float* __restrict__ coords,
        const float* __restrict__ table,
        const float* __restrict__ ws,
        float* __restrict__ out) {
    __shared__ float tl[HH][65];   // [h][idx], pad 65: bank=(h+idx)%32
    int tid = threadIdx.x;
    #pragma unroll
    for (int k = tid; k < NROWS * HH; k += 256) {
        int idx = k >> 4, h = k & 15;
        tl[h][idx] = table[k];
    }

    float range = ws[0];
    int b = blockIdx.x >> 10;
    int i = blockIdx.x & (TT - 1);
    float ei  = coords[(size_t)(b * TT + i) * 2 + 0];
    float pii = coords[(size_t)(b * TT + i) * 2 + 1];
    __syncthreads();

    int j0 = tid * 4;
    const float4* cp = (const float4*)(coords + (size_t)(b * TT + j0) * 2);
    float4 c01 = cp[0];
    float4 c23 = cp[1];
    float ej[4] = {c01.x, c01.z, c23.x, c23.z};
    float pj[4] = {c01.y, c01.w, c23.y, c23.w};

    int eidx[4], pidx[4];
    #pragma unroll
    for (int jj = 0; jj < 4; ++jj) {
        float re = ei - ej[jj];
        int be = (int)(re / range * 16.0f);
        be = min(max(be, -16), 15);
        eidx[jj] = be + 16;
        float w = (pii - pj[jj]) + PI_F;
        float m = fmodf(w, TWOPI_F);
        if (m < 0.0f) m += TWOPI_F;
        float rp = m - PI_F;
        int bp = (int)(rp / PI_F * 16.0f);
        bp = min(max(bp, -16), 15);
        pidx[jj] = bp + 48;
    }

    float* op = out + ((size_t)(b * HH) * TT + i) * TT + j0;
    #pragma unroll
    for (int q = 0; q < 4; ++q) {
        #pragma unroll
        for (int r = 0; r < 4; ++r) {
            int h = q * 4 + r;
            float4 v;
            v.x = tl[h][eidx[0]] + tl[h][pidx[0]];
            v.y = tl[h][eidx[1]] + tl[h][pidx[1]];
            v.z = tl[h][eidx[2]] + tl[h][pidx[2]];
            v.w = tl[h][eidx[3]] + tl[h][pidx[3]];
            *(float4*)(op + (size_t)h * TT * TT) = v;
        }
    }
}

extern "C" void kernel_launch(void* const* d_in, const int* in_sizes, int n_in,
                              void* d_out, int out_size, void* d_ws, size_t ws_size,
                              hipStream_t stream) {
    const float* coords = (const float*)d_in[0];   // [4,1024,2] f32
    const float* table  = (const float*)d_in[1];   // [64,16]   f32
    float* out = (float*)d_out;                    // [4,16,1024,1024] f32
    float* ws  = (float*)d_ws;

    QuantizedRPE_range_kernel<<<1, 256, 0, stream>>>(coords, ws);
    QuantizedRPE_fill_kernel<<<BB * TT, 256, 0, stream>>>(coords, table, ws, out);
}